// Round 1
// baseline (516.401 us; speedup 1.0000x reference)
//
#include <hip/hip_runtime.h>
#include <hip/hip_bf16.h>
#include <math.h>

// Problem constants
#define Bb   32
#define Ss   512
#define Hh   768
#define Dd   64
#define ND   128          // 2*D
#define Mrows (Bb*Ss)     // 16384
#define BIGF 1.0e12f

// ---------------------------------------------------------------------------
// Kernel 1: out = hidden @ dense_w + dense_b, then RoPE, split into q/k.
// Tiling: BM=32 rows, BN=128 (full), BK=32. 256 threads, 4x4 micro-tile.
// ---------------------------------------------------------------------------
__global__ __launch_bounds__(256) void proj_rope_kernel(
    const float* __restrict__ hidden,   // (M, H)
    const float* __restrict__ w,        // (H, 128)
    const float* __restrict__ bias,     // (128,)
    float* __restrict__ qout,           // (M, 64)
    float* __restrict__ kout)           // (M, 64)
{
    __shared__ float At[32][33];        // [row][k], +1 pad
    __shared__ float Bt[32][ND];        // [k][col]

    const int tid = threadIdx.x;
    const int row0 = blockIdx.x * 32;
    const int tx = tid & 31;            // col group: cols tx*4 .. tx*4+3
    const int ty = tid >> 5;            // row group: rows ty*4 .. ty*4+3

    float acc[4][4] = {};

    const float* Abase = hidden + (size_t)row0 * Hh;

    for (int k0 = 0; k0 < Hh; k0 += 32) {
        // Load A tile: 32 rows x 32 k's; one float4 per thread.
        {
            int r  = tid >> 3;          // 0..31
            int c4 = (tid & 7) * 4;     // 0..28
            float4 v = *(const float4*)(Abase + (size_t)r * Hh + k0 + c4);
            At[r][c4 + 0] = v.x; At[r][c4 + 1] = v.y;
            At[r][c4 + 2] = v.z; At[r][c4 + 3] = v.w;
        }
        // Load B tile: 32 k's x 128 cols; 4 float4 per thread.
        {
            int c4 = (tid & 31) * 4;
            int rb = tid >> 5;          // 0..7
            #pragma unroll
            for (int j = 0; j < 4; ++j) {
                int r = rb + j * 8;
                float4 v = *(const float4*)(w + (size_t)(k0 + r) * ND + c4);
                *(float4*)&Bt[r][c4] = v;
            }
        }
        __syncthreads();

        #pragma unroll 8
        for (int kk = 0; kk < 32; ++kk) {
            float4 bv = *(const float4*)&Bt[kk][tx * 4];
            float a[4];
            #pragma unroll
            for (int i = 0; i < 4; ++i) a[i] = At[ty * 4 + i][kk];
            #pragma unroll
            for (int i = 0; i < 4; ++i) {
                acc[i][0] = fmaf(a[i], bv.x, acc[i][0]);
                acc[i][1] = fmaf(a[i], bv.y, acc[i][1]);
                acc[i][2] = fmaf(a[i], bv.z, acc[i][2]);
                acc[i][3] = fmaf(a[i], bv.w, acc[i][3]);
            }
        }
        __syncthreads();
    }

    // Epilogue: bias + RoPE + store to q/k.
    const int c0 = tx * 4;
    float4 bb = *(const float4*)(bias + c0);
    const float bias4[4] = { bb.x, bb.y, bb.z, bb.w };
    const float ln_base = -logf(10000.0f) / 32.0f;  // exponent scale per ifreq

    #pragma unroll
    for (int i = 0; i < 4; ++i) {
        int grow = row0 + ty * 4 + i;
        int spos = grow & (Ss - 1);
        #pragma unroll
        for (int jp = 0; jp < 2; ++jp) {
            int j   = jp * 2;
            int col = c0 + j;                 // even
            int d   = col & (Dd - 1);         // dim within half
            int ifr = d >> 1;
            float inv_freq = expf(ln_base * (float)ifr); // 10000^(-2*ifr/64)
            float ang = (float)spos * inv_freq;
            float sn, cs;
            sincosf(ang, &sn, &cs);
            float x0 = acc[i][j]     + bias4[j];
            float x1 = acc[i][j + 1] + bias4[j + 1];
            float o0 = x0 * cs - x1 * sn;
            float o1 = x1 * cs + x0 * sn;
            float* dst = (col < Dd) ? qout : kout;
            dst[(size_t)grow * Dd + d]     = o0;
            dst[(size_t)grow * Dd + d + 1] = o1;
        }
    }
}

// ---------------------------------------------------------------------------
// Kernel 2: per-row logits + masks + dual logsumexp. One block per (b,m).
// ---------------------------------------------------------------------------
__global__ __launch_bounds__(256) void span_loss_kernel(
    const float* __restrict__ q,        // (M, 64)
    const float* __restrict__ k,        // (M, 64)
    const float* __restrict__ mask,     // (B, S)
    const int*   __restrict__ span,     // (B, S, S)
    double* __restrict__ rowsum)        // (M,)
{
    const int row = blockIdx.x;         // b*S + m
    const int b   = row >> 9;
    const int m   = row & (Ss - 1);
    const int tid = threadIdx.x;

    __shared__ __align__(16) float qs[Dd];
    __shared__ float wred[2][4];

    if (tid < Dd) qs[tid] = q[(size_t)row * Dd + tid];
    __syncthreads();

    float vneg[2], vpos[2];
    #pragma unroll
    for (int e = 0; e < 2; ++e) {
        int n = tid + e * 256;
        const float* krow = k + (size_t)(b * Ss + n) * Dd;
        float dot = 0.0f;
        #pragma unroll
        for (int d4 = 0; d4 < 16; ++d4) {
            float4 kv = *(const float4*)(krow + d4 * 4);
            float4 qv = *(const float4*)(qs + d4 * 4);
            dot = fmaf(qv.x, kv.x, dot);
            dot = fmaf(qv.y, kv.y, dot);
            dot = fmaf(qv.z, kv.z, dot);
            dot = fmaf(qv.w, kv.w, dot);
        }
        float pad   = mask[b * Ss + n];
        float logit = dot * pad - (1.0f - pad) * BIGF;
        if (n < m) logit -= BIGF;       // tril(ones,-1) mask
        logit *= 0.125f;                // / sqrt(64)
        float ft = (float)span[(size_t)row * Ss + n];
        float yp = (1.0f - 2.0f * ft) * logit;
        vneg[e] = yp - ft * BIGF;
        vpos[e] = yp - (1.0f - ft) * BIGF;
    }

    // --- block max (include the appended zero entry: init with 0) ---
    float mneg = fmaxf(fmaxf(vneg[0], vneg[1]), 0.0f);
    float mpos = fmaxf(fmaxf(vpos[0], vpos[1]), 0.0f);
    #pragma unroll
    for (int off = 32; off > 0; off >>= 1) {
        mneg = fmaxf(mneg, __shfl_down(mneg, off));
        mpos = fmaxf(mpos, __shfl_down(mpos, off));
    }
    const int wave = tid >> 6;
    if ((tid & 63) == 0) { wred[0][wave] = mneg; wred[1][wave] = mpos; }
    __syncthreads();
    mneg = fmaxf(fmaxf(wred[0][0], wred[0][1]), fmaxf(wred[0][2], wred[0][3]));
    mpos = fmaxf(fmaxf(wred[1][0], wred[1][1]), fmaxf(wred[1][2], wred[1][3]));
    __syncthreads();

    // --- block sum of exp(v - max) ---
    float sneg = expf(vneg[0] - mneg) + expf(vneg[1] - mneg);
    float spos = expf(vpos[0] - mpos) + expf(vpos[1] - mpos);
    #pragma unroll
    for (int off = 32; off > 0; off >>= 1) {
        sneg += __shfl_down(sneg, off);
        spos += __shfl_down(spos, off);
    }
    if ((tid & 63) == 0) { wred[0][wave] = sneg; wred[1][wave] = spos; }
    __syncthreads();

    if (tid == 0) {
        float SN = wred[0][0] + wred[0][1] + wred[0][2] + wred[0][3]
                 + expf(-mneg);                    // zero entry
        float SP = wred[1][0] + wred[1][1] + wred[1][2] + wred[1][3]
                 + expf(-mpos);
        float lse = (mneg + logf(SN)) + (mpos + logf(SP));
        rowsum[row] = (double)lse;
    }
}

// ---------------------------------------------------------------------------
// Kernel 3: fp64 mean over 16384 row sums -> fp32 scalar.
// ---------------------------------------------------------------------------
__global__ __launch_bounds__(256) void final_reduce_kernel(
    const double* __restrict__ rowsum, float* __restrict__ out)
{
    __shared__ double sh[256];
    const int tid = threadIdx.x;
    double s = 0.0;
    for (int i = tid; i < Mrows; i += 256) s += rowsum[i];
    sh[tid] = s;
    __syncthreads();
    for (int off = 128; off > 0; off >>= 1) {
        if (tid < off) sh[tid] += sh[tid + off];
        __syncthreads();
    }
    if (tid == 0) out[0] = (float)(sh[0] / (double)Mrows);
}

// ---------------------------------------------------------------------------
extern "C" void kernel_launch(void* const* d_in, const int* in_sizes, int n_in,
                              void* d_out, int out_size, void* d_ws, size_t ws_size,
                              hipStream_t stream)
{
    const float* hidden = (const float*)d_in[0];   // (B,S,H)
    const float* mask   = (const float*)d_in[1];   // (B,S)
    const int*   span   = (const int*)  d_in[2];   // (B,S,S)
    const float* w      = (const float*)d_in[3];   // (H, 2D)
    const float* bias   = (const float*)d_in[4];   // (2D,)
    float* out = (float*)d_out;

    // ws layout: [rowsum: 16384 doubles][q: 16384*64 f32][k: 16384*64 f32]
    double* rowsum = (double*)d_ws;
    float*  qbuf   = (float*)((char*)d_ws + (size_t)Mrows * sizeof(double));
    float*  kbuf   = qbuf + (size_t)Mrows * Dd;

    proj_rope_kernel<<<Mrows / 32, 256, 0, stream>>>(hidden, w, bias, qbuf, kbuf);
    span_loss_kernel<<<Mrows, 256, 0, stream>>>(qbuf, kbuf, mask, span, rowsum);
    final_reduce_kernel<<<1, 256, 0, stream>>>(rowsum, out);
}

// Round 2
// 260.940 us; speedup vs baseline: 1.9790x; 1.9790x over previous
//
#include <hip/hip_runtime.h>
#include <hip/hip_bf16.h>
#include <math.h>

// Problem constants
#define Bb   32
#define Ss   512
#define Hh   768
#define Dd   64
#define ND   128          // 2*D
#define Mrows (Bb*Ss)     // 16384
#define BIGF 1.0e12f

// ---------------------------------------------------------------------------
// Kernel 1: out = hidden @ dense_w + dense_b, then RoPE, split into q/k.
// BM=64, BN=128 (full), BK=32. 256 threads, 8x4 micro-tile.
// A stored k-major in LDS -> micro-tile A reads are same-address broadcasts.
// ---------------------------------------------------------------------------
__global__ __launch_bounds__(256) void proj_rope_kernel(
    const float* __restrict__ hidden,   // (M, H)
    const float* __restrict__ w,        // (H, 128)
    const float* __restrict__ bias,     // (128,)
    float* __restrict__ qout,           // (M, 64)
    float* __restrict__ kout)           // (M, 64)
{
    __shared__ float At[32][64];        // [k][row]   8 KB
    __shared__ float Bt[32][ND];        // [k][col]  16 KB

    const int tid  = threadIdx.x;
    const int row0 = blockIdx.x * 64;
    const int tx   = tid & 31;          // col group: cols tx*4 .. +3
    const int ty   = tid >> 5;          // row group: rows ty*8 .. +7

    float acc[8][4] = {};

    for (int k0 = 0; k0 < Hh; k0 += 32) {
        // ---- A tile: 64 rows x 32 k, loaded coalesced, stored transposed.
        {
            int r  = tid >> 2;              // 0..63
            int c0 = (tid & 3) * 4;         // 0,4,8,12
            const float* src = hidden + (size_t)(row0 + r) * Hh + k0 + c0;
            float4 v0 = *(const float4*)(src);
            float4 v1 = *(const float4*)(src + 16);
            At[c0 + 0][r] = v0.x; At[c0 + 1][r] = v0.y;
            At[c0 + 2][r] = v0.z; At[c0 + 3][r] = v0.w;
            At[c0 + 16][r] = v1.x; At[c0 + 17][r] = v1.y;
            At[c0 + 18][r] = v1.z; At[c0 + 19][r] = v1.w;
        }
        // ---- B tile: 32 k x 128 cols; 4 float4 per thread, coalesced.
        {
            int c4 = (tid & 31) * 4;
            int rb = tid >> 5;              // 0..7
            #pragma unroll
            for (int j = 0; j < 4; ++j) {
                int r = rb + j * 8;
                float4 v = *(const float4*)(w + (size_t)(k0 + r) * ND + c4);
                *(float4*)&Bt[r][c4] = v;
            }
        }
        __syncthreads();

        #pragma unroll 8
        for (int kk = 0; kk < 32; ++kk) {
            float4 a0 = *(const float4*)&At[kk][ty * 8];      // broadcast
            float4 a1 = *(const float4*)&At[kk][ty * 8 + 4];  // broadcast
            float4 bv = *(const float4*)&Bt[kk][tx * 4];
            float a[8] = { a0.x, a0.y, a0.z, a0.w, a1.x, a1.y, a1.z, a1.w };
            #pragma unroll
            for (int i = 0; i < 8; ++i) {
                acc[i][0] = fmaf(a[i], bv.x, acc[i][0]);
                acc[i][1] = fmaf(a[i], bv.y, acc[i][1]);
                acc[i][2] = fmaf(a[i], bv.z, acc[i][2]);
                acc[i][3] = fmaf(a[i], bv.w, acc[i][3]);
            }
        }
        __syncthreads();
    }

    // ---- Epilogue: bias + RoPE + store to q/k (float2 per pair).
    const int c0 = tx * 4;
    float4 bb = *(const float4*)(bias + c0);
    const float bias4[4] = { bb.x, bb.y, bb.z, bb.w };
    const float ln_base = -logf(10000.0f) / 32.0f;

    #pragma unroll
    for (int i = 0; i < 8; ++i) {
        int grow = row0 + ty * 8 + i;
        int spos = grow & (Ss - 1);
        #pragma unroll
        for (int jp = 0; jp < 2; ++jp) {
            int j   = jp * 2;
            int col = c0 + j;                 // even
            int d   = col & (Dd - 1);
            int ifr = d >> 1;
            float inv_freq = expf(ln_base * (float)ifr);
            float ang = (float)spos * inv_freq;
            float sn, cs;
            sincosf(ang, &sn, &cs);
            float x0 = acc[i][j]     + bias4[j];
            float x1 = acc[i][j + 1] + bias4[j + 1];
            float2 o = make_float2(x0 * cs - x1 * sn, x1 * cs + x0 * sn);
            float* dst = (col < Dd) ? qout : kout;
            *(float2*)(dst + (size_t)grow * Dd + d) = o;
        }
    }
}

// ---------------------------------------------------------------------------
// Kernel 2: per-batch-slice logits + masks + dual logsumexp.
// Grid: 32 batches x 8 slices of 64 rows. 512 threads; thread n owns k-col n
// in registers. q slice in LDS (broadcast reads). 4 rows per reduction round.
// ---------------------------------------------------------------------------
__global__ __launch_bounds__(512) void span_loss_kernel(
    const float* __restrict__ q,        // (M, 64)
    const float* __restrict__ k,        // (M, 64)
    const float* __restrict__ mask,     // (B, S)
    const int*   __restrict__ span,     // (B, S, S)
    double* __restrict__ rowsum)        // (M,)
{
    const int b    = blockIdx.x >> 3;
    const int m0   = (blockIdx.x & 7) * 64;   // first row (within batch)
    const int tid  = threadIdx.x;             // 0..511 == column n
    const int n    = tid;
    const int wave = tid >> 6;
    const int lane = tid & 63;

    __shared__ __align__(16) float qs[64][64];   // 16 KB
    __shared__ float wmax[8][8];                  // [value][wave]
    __shared__ float wsum[8][8];

    // k column -> registers (256 B contiguous per thread; wave covers 16 KB).
    float4 kreg[16];
    {
        const float4* krow = (const float4*)(k + (size_t)(b * Ss + n) * Dd);
        #pragma unroll
        for (int i = 0; i < 16; ++i) kreg[i] = krow[i];
    }
    const float pad = mask[b * Ss + n];

    // stage q slice (64 rows) coalesced
    {
        const float4* qsrc = (const float4*)(q + (size_t)(b * Ss + m0) * Dd);
        float4* qdst = (float4*)&qs[0][0];
        qdst[tid]       = qsrc[tid];
        qdst[tid + 512] = qsrc[tid + 512];
    }
    __syncthreads();

    const int* sp_base = span + ((size_t)(b * Ss + m0)) * Ss + n;

    int sp[4];
    #pragma unroll
    for (int j = 0; j < 4; ++j) sp[j] = sp_base[(size_t)j * Ss];

    #pragma unroll 1
    for (int g = 0; g < 16; ++g) {
        const int r0 = g * 4;
        // prefetch next group's span
        int spn[4];
        if (g < 15) {
            #pragma unroll
            for (int j = 0; j < 4; ++j)
                spn[j] = sp_base[(size_t)(r0 + 4 + j) * Ss];
        }

        // ---- dots for 4 rows
        float dt[4] = {0.f, 0.f, 0.f, 0.f};
        const float4* q0 = (const float4*)&qs[r0][0];
        #pragma unroll
        for (int d4 = 0; d4 < 16; ++d4) {
            float4 kv = kreg[d4];
            #pragma unroll
            for (int j = 0; j < 4; ++j) {
                float4 qv = q0[j * 16 + d4];      // broadcast
                dt[j] = fmaf(qv.x, kv.x, dt[j]);
                dt[j] = fmaf(qv.y, kv.y, dt[j]);
                dt[j] = fmaf(qv.z, kv.z, dt[j]);
                dt[j] = fmaf(qv.w, kv.w, dt[j]);
            }
        }

        // ---- elementwise epilogue -> vneg/vpos per row
        float vneg[4], vpos[4];
        #pragma unroll
        for (int j = 0; j < 4; ++j) {
            int m = m0 + r0 + j;                  // row within batch
            float logit = dt[j] * pad - (1.0f - pad) * BIGF;
            if (n < m) logit -= BIGF;
            logit *= 0.125f;
            float ft = (float)sp[j];
            float yp = (1.0f - 2.0f * ft) * logit;
            vneg[j] = yp - ft * BIGF;
            vpos[j] = yp - (1.0f - ft) * BIGF;
        }

        // ---- block max (zero entry folded via init-with-0)
        float mx[8];
        #pragma unroll
        for (int j = 0; j < 4; ++j) {
            mx[j]     = fmaxf(vneg[j], 0.0f);
            mx[4 + j] = fmaxf(vpos[j], 0.0f);
        }
        #pragma unroll
        for (int off = 32; off > 0; off >>= 1) {
            #pragma unroll
            for (int v = 0; v < 8; ++v)
                mx[v] = fmaxf(mx[v], __shfl_xor(mx[v], off));
        }
        if (lane == 0) {
            #pragma unroll
            for (int v = 0; v < 8; ++v) wmax[v][wave] = mx[v];
        }
        __syncthreads();
        float bm[8];
        #pragma unroll
        for (int v = 0; v < 8; ++v) {
            float t = wmax[v][0];
            #pragma unroll
            for (int ww = 1; ww < 8; ++ww) t = fmaxf(t, wmax[v][ww]);
            bm[v] = t;
        }

        // ---- block sum of exp
        float sm[8];
        #pragma unroll
        for (int j = 0; j < 4; ++j) {
            sm[j]     = __expf(vneg[j] - bm[j]);
            sm[4 + j] = __expf(vpos[j] - bm[4 + j]);
        }
        #pragma unroll
        for (int off = 32; off > 0; off >>= 1) {
            #pragma unroll
            for (int v = 0; v < 8; ++v)
                sm[v] += __shfl_xor(sm[v], off);
        }
        if (lane == 0) {
            #pragma unroll
            for (int v = 0; v < 8; ++v) wsum[v][wave] = sm[v];
        }
        __syncthreads();

        if (tid < 4) {
            int j = tid;
            float SN = __expf(-bm[j]);            // appended zero entry
            float SP = __expf(-bm[4 + j]);
            #pragma unroll
            for (int ww = 0; ww < 8; ++ww) {
                SN += wsum[j][ww];
                SP += wsum[4 + j][ww];
            }
            float lse = (bm[j] + logf(SN)) + (bm[4 + j] + logf(SP));
            rowsum[(size_t)(b * Ss + m0 + r0 + j)] = (double)lse;
        }

        #pragma unroll
        for (int j = 0; j < 4; ++j) sp[j] = spn[j];
    }
}

// ---------------------------------------------------------------------------
// Kernel 3: fp64 mean over 16384 row sums -> fp32 scalar.
// ---------------------------------------------------------------------------
__global__ __launch_bounds__(256) void final_reduce_kernel(
    const double* __restrict__ rowsum, float* __restrict__ out)
{
    __shared__ double sh[256];
    const int tid = threadIdx.x;
    double s = 0.0;
    for (int i = tid; i < Mrows; i += 256) s += rowsum[i];
    sh[tid] = s;
    __syncthreads();
    for (int off = 128; off > 0; off >>= 1) {
        if (tid < off) sh[tid] += sh[tid + off];
        __syncthreads();
    }
    if (tid == 0) out[0] = (float)(sh[0] / (double)Mrows);
}

// ---------------------------------------------------------------------------
extern "C" void kernel_launch(void* const* d_in, const int* in_sizes, int n_in,
                              void* d_out, int out_size, void* d_ws, size_t ws_size,
                              hipStream_t stream)
{
    const float* hidden = (const float*)d_in[0];   // (B,S,H)
    const float* mask   = (const float*)d_in[1];   // (B,S)
    const int*   span   = (const int*)  d_in[2];   // (B,S,S)
    const float* w      = (const float*)d_in[3];   // (H, 2D)
    const float* bias   = (const float*)d_in[4];   // (2D,)
    float* out = (float*)d_out;

    // ws layout: [rowsum: 16384 doubles][q: 16384*64 f32][k: 16384*64 f32]
    double* rowsum = (double*)d_ws;
    float*  qbuf   = (float*)((char*)d_ws + (size_t)Mrows * sizeof(double));
    float*  kbuf   = qbuf + (size_t)Mrows * Dd;

    proj_rope_kernel<<<Mrows / 64, 256, 0, stream>>>(hidden, w, bias, qbuf, kbuf);
    span_loss_kernel<<<Bb * 8, 512, 0, stream>>>(qbuf, kbuf, mask, span, rowsum);
    final_reduce_kernel<<<1, 256, 0, stream>>>(rowsum, out);
}